// Round 5
// baseline (1124.119 us; speedup 1.0000x reference)
//
#include <hip/hip_runtime.h>

#define F 128
#define NB 4
#define NR 8

typedef __attribute__((ext_vector_type(8))) short bf16x8;
typedef __attribute__((ext_vector_type(4))) float f32x4;
typedef __attribute__((ext_vector_type(2))) float f32x2;

__device__ __forceinline__ unsigned f2bf(float f) {  // RNE f32->bf16
    unsigned u = __float_as_uint(f);
    return (u + 0x7FFFu + ((u >> 16) & 1u)) >> 16;
}
__device__ __forceinline__ unsigned f2bf2(float lo, float hi) {
    return f2bf(lo) | (f2bf(hi) << 16);
}

// x f32 [N*128] -> bf16, 8 elems/thread
__global__ void cvt_x_kernel(const float4* __restrict__ x4, uint4* __restrict__ xb, int total8) {
    int i = blockIdx.x * blockDim.x + threadIdx.x;
    if (i >= total8) return;
    float4 a = x4[(size_t)i * 2], b = x4[(size_t)i * 2 + 1];
    xb[i] = make_uint4(f2bf2(a.x, a.y), f2bf2(a.z, a.w), f2bf2(b.x, b.y), f2bf2(b.z, b.w));
}

// Bt[o][b*128+k] = bf16(W_basis[b][k][o]) : [128][512]
__global__ void cvt_w_kernel(const float* __restrict__ Wb, unsigned short* __restrict__ Bt) {
    int t = blockIdx.x * blockDim.x + threadIdx.x;
    if (t >= F * NB * F) return;
    int o = t >> 9, bk = t & 511, b = bk >> 7, k = bk & 127;
    Bt[t] = (unsigned short)f2bf(Wb[((size_t)b * F + k) * F + o]);
}

// count per (dst,rel); store per-edge rank (uint8, coalesced).
__global__ void hist_kernel(const int* __restrict__ ed, int* __restrict__ cnt,
                            unsigned char* __restrict__ rank, int E) {
    int e = (blockIdx.x * blockDim.x + threadIdx.x) * 4;
    if (e >= E) return;
    int r = blockIdx.y;
    size_t idx = (size_t)r * E + e;
    if (e + 3 < E) {
        int4 d4 = *(const int4*)&ed[idx];
        uchar4 rk;
        rk.x = (unsigned char)atomicAdd(&cnt[d4.x * 8 + r], 1);
        rk.y = (unsigned char)atomicAdd(&cnt[d4.y * 8 + r], 1);
        rk.z = (unsigned char)atomicAdd(&cnt[d4.z * 8 + r], 1);
        rk.w = (unsigned char)atomicAdd(&cnt[d4.w * 8 + r], 1);
        *(uchar4*)&rank[idx] = rk;
    } else {
        for (int k = 0; e + k < E; ++k)
            rank[idx + k] = (unsigned char)atomicAdd(&cnt[ed[idx + k] * 8 + r], 1);
    }
}

// exclusive scan over M = N*8 counts -> offs[M+1]
__global__ __launch_bounds__(1024) void scan_kernel(const int* __restrict__ cnt,
                                                    int* __restrict__ offs, int M) {
    __shared__ int sums[1024];
    int t = threadIdx.x;
    int ch = (M + 1023) >> 10;
    int beg = min(t * ch, M), end = min(beg + ch, M);
    int s = 0;
    for (int i = beg; i < end; ++i) s += cnt[i];
    sums[t] = s;
    __syncthreads();
    for (int dd = 1; dd < 1024; dd <<= 1) {
        int v = (t >= dd) ? sums[t - dd] : 0;
        __syncthreads();
        sums[t] += v;
        __syncthreads();
    }
    int run = (t == 0) ? 0 : sums[t - 1];
    for (int i = beg; i < end; ++i) {
        offs[i] = run;
        run += cnt[i];
    }
    if (t == 1023) offs[M] = run;
}

// place packed (src:16 | val-bf16:16) at offs[d*8+r] + rank. No atomics.
__global__ void fill_kernel(const int* __restrict__ es, const float* __restrict__ ev,
                            const int* __restrict__ ed, const int* __restrict__ offs,
                            const unsigned char* __restrict__ rank,
                            unsigned* __restrict__ payload, int E) {
    int e = (blockIdx.x * blockDim.x + threadIdx.x) * 4;
    if (e >= E) return;
    int r = blockIdx.y;
    size_t idx = (size_t)r * E + e;
    if (e + 3 < E) {
        int4 s4 = *(const int4*)&es[idx];
        int4 d4 = *(const int4*)&ed[idx];
        float4 v4 = *(const float4*)&ev[idx];
        uchar4 rk = *(const uchar4*)&rank[idx];
        payload[offs[d4.x * 8 + r] + rk.x] = (unsigned)(s4.x & 0xFFFF) | (f2bf(v4.x) << 16);
        payload[offs[d4.y * 8 + r] + rk.y] = (unsigned)(s4.y & 0xFFFF) | (f2bf(v4.y) << 16);
        payload[offs[d4.z * 8 + r] + rk.z] = (unsigned)(s4.z & 0xFFFF) | (f2bf(v4.z) << 16);
        payload[offs[d4.w * 8 + r] + rk.w] = (unsigned)(s4.w & 0xFFFF) | (f2bf(v4.w) << 16);
    } else {
        for (int k = 0; e + k < E; ++k)
            payload[offs[ed[idx + k] * 8 + r] + rank[idx + k]] =
                (unsigned)(es[idx + k] & 0xFFFF) | (f2bf(ev[idx + k]) << 16);
    }
}

// one wave per dst: 8 contiguous relation segments, cw hoisted per segment,
// gather bf16 x rows, f32x2 packed accumulate, write mix row as packed bf16.
__global__ __launch_bounds__(256) void accum_kernel(const unsigned* __restrict__ xb,
                                                    const unsigned* __restrict__ payload,
                                                    const int* __restrict__ offs,
                                                    const float* __restrict__ comp,
                                                    unsigned* __restrict__ mix,
                                                    int c0, int c1) {
    __shared__ float4 scomp[NR];
    if (threadIdx.x < NR) scomp[threadIdx.x] = ((const float4*)comp)[threadIdx.x];
    __syncthreads();
    int wave = threadIdx.x >> 6, lane = threadIdx.x & 63;
    int d = c0 + blockIdx.x * 4 + wave;
    if (d >= c1) return;
    uint4 oA = *(const uint4*)&offs[d * 8];
    uint4 oB = *(const uint4*)&offs[d * 8 + 4];
    unsigned oE = (unsigned)offs[d * 8 + 8];
    unsigned bnd[9] = {oA.x, oA.y, oA.z, oA.w, oB.x, oB.y, oB.z, oB.w, oE};

    f32x2 a0 = {0.f, 0.f}, a1 = {0.f, 0.f}, a2 = {0.f, 0.f}, a3 = {0.f, 0.f};
#pragma unroll
    for (int r = 0; r < NR; ++r) {
        float4 cw = scomp[r];
        unsigned j = bnd[r], je = bnd[r + 1];
        auto edge = [&](unsigned p) {
            unsigned g = xb[(size_t)(p & 0xFFFFu) * 64 + lane];
            float v = __uint_as_float(p & 0xFFFF0000u);
            f32x2 xv = {__uint_as_float(g << 16), __uint_as_float(g & 0xFFFF0000u)};
            a0 += xv * (v * cw.x);
            a1 += xv * (v * cw.y);
            a2 += xv * (v * cw.z);
            a3 += xv * (v * cw.w);
        };
        if ((j & 1u) && j < je) { edge(payload[j]); ++j; }
        for (; j + 2 <= je; j += 2) {
            uint2 pk = *(const uint2*)&payload[j];
            edge(pk.x);
            edge(pk.y);
        }
        if (j < je) edge(payload[j]);
    }
    unsigned* mrow = mix + (size_t)(d - c0) * 256 + lane;
    mrow[0]   = f2bf2(a0.x, a0.y);
    mrow[64]  = f2bf2(a1.x, a1.y);
    mrow[128] = f2bf2(a2.x, a2.y);
    mrow[192] = f2bf2(a3.x, a3.y);
}

// out[gbase+row][o] = relu( sum_K mix[row][K] * Bt[o][K] ), K=512.
// 4 waves, tile 128x128, BK=64, XOR-swizzled LDS, MFMA 16x16x32 bf16.
__global__ __launch_bounds__(256) void gemm_mfma(const unsigned short* __restrict__ mix,
                                                 const unsigned short* __restrict__ Bt,
                                                 float* __restrict__ out,
                                                 int rows, int gbase, int N) {
    __shared__ unsigned short As[128 * 64];
    __shared__ unsigned short Bs[128 * 64];
    const int t = threadIdx.x;
    const int row0 = blockIdx.x * 128;
    const int w = t >> 6, lane = t & 63;
    f32x4 acc[2][8] = {};

    for (int kt = 0; kt < 8; ++kt) {
        __syncthreads();
        for (int u = t; u < 1024; u += 256) {
            int r = u >> 3, c = u & 7;
            int k8 = c * 8;
            int ks = k8 ^ ((r & 7) << 3);
            uint4 av = make_uint4(0, 0, 0, 0);
            if (row0 + r < rows) av = *(const uint4*)&mix[(size_t)(row0 + r) * 512 + kt * 64 + k8];
            *(uint4*)&As[r * 64 + ks] = av;
            uint4 bv = *(const uint4*)&Bt[(size_t)r * 512 + kt * 64 + k8];
            *(uint4*)&Bs[r * 64 + ks] = bv;
        }
        __syncthreads();
#pragma unroll
        for (int ks = 0; ks < 2; ++ks) {
            bf16x8 a[2], b[8];
            const int kbase = ks * 32 + (lane >> 4) * 8;
#pragma unroll
            for (int i = 0; i < 2; ++i) {
                int r = w * 32 + i * 16 + (lane & 15);
                int kk = kbase ^ ((r & 7) << 3);
                a[i] = *(bf16x8*)&As[r * 64 + kk];
            }
#pragma unroll
            for (int jj = 0; jj < 8; ++jj) {
                int o = jj * 16 + (lane & 15);
                int kk = kbase ^ ((o & 7) << 3);
                b[jj] = *(bf16x8*)&Bs[o * 64 + kk];
            }
#pragma unroll
            for (int i = 0; i < 2; ++i)
#pragma unroll
                for (int jj = 0; jj < 8; ++jj)
                    acc[i][jj] = __builtin_amdgcn_mfma_f32_16x16x32_bf16(a[i], b[jj], acc[i][jj], 0, 0, 0);
        }
    }

#pragma unroll
    for (int i = 0; i < 2; ++i) {
        int mbase = w * 32 + i * 16 + (lane >> 4) * 4;
#pragma unroll
        for (int q = 0; q < 4; ++q) {
            int m = mbase + q;
            int gr = gbase + row0 + m;
            if (row0 + m < rows && gr < N) {
#pragma unroll
                for (int jj = 0; jj < 8; ++jj) {
                    int n = jj * 16 + (lane & 15);
                    out[(size_t)gr * F + n] = fmaxf(acc[i][jj][q], 0.f);
                }
            }
        }
    }
}

extern "C" void kernel_launch(void* const* d_in, const int* in_sizes, int n_in,
                              void* d_out, int out_size, void* d_ws, size_t ws_size,
                              hipStream_t stream) {
    const float* x  = (const float*)d_in[0];
    const float* Wb = (const float*)d_in[1];
    const float* Wc = (const float*)d_in[2];
    const float* ev = (const float*)d_in[3];
    const int*   es = (const int*)d_in[4];
    const int*   ed = (const int*)d_in[5];
    float* out = (float*)d_out;

    const int N = in_sizes[0] / F;
    const int E = in_sizes[3] / NR;

    char* p = (char*)d_ws;
    auto alloc = [&](size_t bytes) -> char* {
        char* q = p;
        p += (bytes + 255) & ~(size_t)255;
        return q;
    };
    unsigned* payload   = (unsigned*)alloc((size_t)NR * E * 4);        // 16 MB
    int* cnt            = (int*)alloc((size_t)N * NR * 4);             // 1.6 MB
    int* offs           = (int*)alloc(((size_t)N * NR + 1) * 4);       // 1.6 MB
    unsigned char* rank = (unsigned char*)alloc((size_t)NR * E);       // 4 MB
    unsigned short* Bt  = (unsigned short*)alloc((size_t)F * NB * F * 2);
    unsigned* xb        = (unsigned*)alloc((size_t)N * F * 2);         // 12.8 MB

    size_t used = (size_t)(p - (char*)d_ws);
    size_t rem = ws_size > used ? ws_size - used : (size_t)(128 * 1024);
    size_t mix_rows = (rem / (512 * 2)) & ~(size_t)127;
    int chunk = (int)(mix_rows < 128 ? 128
                      : (mix_rows > (size_t)N ? (size_t)((N + 127) & ~(size_t)127) : mix_rows));
    unsigned short* mixbuf = (unsigned short*)p;

    hipMemsetAsync(cnt, 0, (size_t)N * NR * 4, stream);
    cvt_x_kernel<<<(N * F / 8 + 255) / 256, 256, 0, stream>>>((const float4*)x, (uint4*)xb, N * F / 8);
    cvt_w_kernel<<<(F * NB * F + 255) / 256, 256, 0, stream>>>(Wb, Bt);

    dim3 eg(((E + 3) / 4 + 255) / 256, NR);
    hist_kernel<<<eg, 256, 0, stream>>>(ed, cnt, rank, E);
    scan_kernel<<<1, 1024, 0, stream>>>(cnt, offs, N * NR);
    fill_kernel<<<eg, 256, 0, stream>>>(es, ev, ed, offs, rank, payload, E);

    for (int c0 = 0; c0 < N; c0 += chunk) {
        int crows = min(chunk, N - c0);
        accum_kernel<<<(crows + 3) / 4, 256, 0, stream>>>(xb, payload, offs, Wc,
                                                          (unsigned*)mixbuf, c0, c0 + crows);
        gemm_mfma<<<(crows + 127) / 128, 256, 0, stream>>>(mixbuf, Bt, out, crows, c0, N);
    }
}

// Round 6
// 558.249 us; speedup vs baseline: 2.0137x; 2.0137x over previous
//
#include <hip/hip_runtime.h>

#define F 128
#define NB 4
#define NR 8

typedef __attribute__((ext_vector_type(8))) short bf16x8;
typedef __attribute__((ext_vector_type(4))) float f32x4;
typedef __attribute__((ext_vector_type(2))) float f32x2;

__device__ __forceinline__ unsigned f2bf(float f) {  // RNE f32->bf16
    unsigned u = __float_as_uint(f);
    return (u + 0x7FFFu + ((u >> 16) & 1u)) >> 16;
}
__device__ __forceinline__ unsigned f2bf2(float lo, float hi) {
    return f2bf(lo) | (f2bf(hi) << 16);
}

// x f32 [N*128] -> bf16, 8 elems/thread
__global__ void cvt_x_kernel(const float4* __restrict__ x4, uint4* __restrict__ xb, int total8) {
    int i = blockIdx.x * blockDim.x + threadIdx.x;
    if (i >= total8) return;
    float4 a = x4[(size_t)i * 2], b = x4[(size_t)i * 2 + 1];
    xb[i] = make_uint4(f2bf2(a.x, a.y), f2bf2(a.z, a.w), f2bf2(b.x, b.y), f2bf2(b.z, b.w));
}

// Bt[o][b*128+k] = bf16(W_basis[b][k][o]) : [128][512]
__global__ void cvt_w_kernel(const float* __restrict__ Wb, unsigned short* __restrict__ Bt) {
    int t = blockIdx.x * blockDim.x + threadIdx.x;
    if (t >= F * NB * F) return;
    int o = t >> 9, bk = t & 511, b = bk >> 7, k = bk & 127;
    Bt[t] = (unsigned short)f2bf(Wb[((size_t)b * F + k) * F + o]);
}

// count per (rel,dst) into cnt[r*N+d]; store per-edge rank (uint8, coalesced).
__global__ void hist_kernel(const int* __restrict__ ed, int* __restrict__ cnt,
                            unsigned char* __restrict__ rank, int E, int N) {
    int e = (blockIdx.x * blockDim.x + threadIdx.x) * 4;
    if (e >= E) return;
    int r = blockIdx.y;
    size_t idx = (size_t)r * E + e;
    int* c = cnt + (size_t)r * N;
    if (e + 3 < E) {
        int4 d4 = *(const int4*)&ed[idx];
        uchar4 rk;
        rk.x = (unsigned char)atomicAdd(&c[d4.x], 1);
        rk.y = (unsigned char)atomicAdd(&c[d4.y], 1);
        rk.z = (unsigned char)atomicAdd(&c[d4.z], 1);
        rk.w = (unsigned char)atomicAdd(&c[d4.w], 1);
        *(uchar4*)&rank[idx] = rk;
    } else {
        for (int k = 0; e + k < E; ++k)
            rank[idx + k] = (unsigned char)atomicAdd(&c[ed[idx + k]], 1);
    }
}

// per-relation exclusive scan: one block per relation over N counts.
__global__ __launch_bounds__(1024) void scan_kernel(const int* __restrict__ cnt,
                                                    int* __restrict__ offs, int N) {
    __shared__ int sums[1024];
    int r = blockIdx.x;
    const int* c = cnt + (size_t)r * N;
    int* o = offs + (size_t)r * (N + 1);
    int t = threadIdx.x;
    int ch = (N + 1023) >> 10;
    int beg = min(t * ch, N), end = min(beg + ch, N);
    int s = 0;
    for (int i = beg; i < end; ++i) s += c[i];
    sums[t] = s;
    __syncthreads();
    for (int dd = 1; dd < 1024; dd <<= 1) {
        int v = (t >= dd) ? sums[t - dd] : 0;
        __syncthreads();
        sums[t] += v;
        __syncthreads();
    }
    int run = (t == 0) ? 0 : sums[t - 1];
    for (int i = beg; i < end; ++i) {
        o[i] = run;
        run += c[i];
    }
    if (t == 1023) o[N] = run;
}

// place packed (src:16 | val-bf16:16) at r*E + offs[r][d] + rank. No atomics.
__global__ void fill_kernel(const int* __restrict__ es, const float* __restrict__ ev,
                            const int* __restrict__ ed, const int* __restrict__ offs,
                            const unsigned char* __restrict__ rank,
                            unsigned* __restrict__ payload, int E, int N) {
    int e = (blockIdx.x * blockDim.x + threadIdx.x) * 4;
    if (e >= E) return;
    int r = blockIdx.y;
    size_t idx = (size_t)r * E + e;
    const int* o = offs + (size_t)r * (N + 1);
    unsigned* pl = payload + (size_t)r * E;
    if (e + 3 < E) {
        int4 s4 = *(const int4*)&es[idx];
        int4 d4 = *(const int4*)&ed[idx];
        float4 v4 = *(const float4*)&ev[idx];
        uchar4 rk = *(const uchar4*)&rank[idx];
        pl[o[d4.x] + rk.x] = (unsigned)(s4.x & 0xFFFF) | (f2bf(v4.x) << 16);
        pl[o[d4.y] + rk.y] = (unsigned)(s4.y & 0xFFFF) | (f2bf(v4.y) << 16);
        pl[o[d4.z] + rk.z] = (unsigned)(s4.z & 0xFFFF) | (f2bf(v4.z) << 16);
        pl[o[d4.w] + rk.w] = (unsigned)(s4.w & 0xFFFF) | (f2bf(v4.w) << 16);
    } else {
        for (int k = 0; e + k < E; ++k)
            pl[o[ed[idx + k]] + rank[idx + k]] =
                (unsigned)(es[idx + k] & 0xFFFF) | (f2bf(ev[idx + k]) << 16);
    }
}

// one wave per dst: 8 relation segments, cw hoisted per segment,
// gather bf16 x rows, f32x2 packed accumulate, write mix row as packed bf16.
__global__ __launch_bounds__(256) void accum_kernel(const unsigned* __restrict__ xb,
                                                    const unsigned* __restrict__ payload,
                                                    const int* __restrict__ offs,
                                                    const float* __restrict__ comp,
                                                    unsigned* __restrict__ mix,
                                                    int c0, int c1, int E, int N) {
    __shared__ float4 scomp[NR];
    if (threadIdx.x < NR) scomp[threadIdx.x] = ((const float4*)comp)[threadIdx.x];
    __syncthreads();
    int wave = threadIdx.x >> 6, lane = threadIdx.x & 63;
    int d = c0 + blockIdx.x * 4 + wave;
    if (d >= c1) return;

    f32x2 a0 = {0.f, 0.f}, a1 = {0.f, 0.f}, a2 = {0.f, 0.f}, a3 = {0.f, 0.f};
#pragma unroll
    for (int r = 0; r < NR; ++r) {
        float4 cw = scomp[r];
        const int* o = offs + (size_t)r * (N + 1) + d;
        unsigned j = (unsigned)o[0], je = (unsigned)o[1];
        const unsigned* pl = payload + (size_t)r * E;
        auto edge = [&](unsigned p) {
            unsigned g = xb[(size_t)(p & 0xFFFFu) * 64 + lane];
            float v = __uint_as_float(p & 0xFFFF0000u);
            f32x2 xv = {__uint_as_float(g << 16), __uint_as_float(g & 0xFFFF0000u)};
            a0 += xv * (v * cw.x);
            a1 += xv * (v * cw.y);
            a2 += xv * (v * cw.z);
            a3 += xv * (v * cw.w);
        };
        if ((j & 1u) && j < je) { edge(pl[j]); ++j; }
        for (; j + 2 <= je; j += 2) {
            uint2 pk = *(const uint2*)&pl[j];
            edge(pk.x);
            edge(pk.y);
        }
        if (j < je) edge(pl[j]);
    }
    unsigned* mrow = mix + (size_t)(d - c0) * 256 + lane;
    mrow[0]   = f2bf2(a0.x, a0.y);
    mrow[64]  = f2bf2(a1.x, a1.y);
    mrow[128] = f2bf2(a2.x, a2.y);
    mrow[192] = f2bf2(a3.x, a3.y);
}

// out[gbase+row][o] = relu( sum_K mix[row][K] * Bt[o][K] ), K=512.
// 4 waves, tile 128x128, BK=64, XOR-swizzled LDS, MFMA 16x16x32 bf16.
__global__ __launch_bounds__(256) void gemm_mfma(const unsigned short* __restrict__ mix,
                                                 const unsigned short* __restrict__ Bt,
                                                 float* __restrict__ out,
                                                 int rows, int gbase, int N) {
    __shared__ unsigned short As[128 * 64];
    __shared__ unsigned short Bs[128 * 64];
    const int t = threadIdx.x;
    const int row0 = blockIdx.x * 128;
    const int w = t >> 6, lane = t & 63;
    f32x4 acc[2][8] = {};

    for (int kt = 0; kt < 8; ++kt) {
        __syncthreads();
        for (int u = t; u < 1024; u += 256) {
            int r = u >> 3, c = u & 7;
            int k8 = c * 8;
            int ks = k8 ^ ((r & 7) << 3);
            uint4 av = make_uint4(0, 0, 0, 0);
            if (row0 + r < rows) av = *(const uint4*)&mix[(size_t)(row0 + r) * 512 + kt * 64 + k8];
            *(uint4*)&As[r * 64 + ks] = av;
            uint4 bv = *(const uint4*)&Bt[(size_t)r * 512 + kt * 64 + k8];
            *(uint4*)&Bs[r * 64 + ks] = bv;
        }
        __syncthreads();
#pragma unroll
        for (int ks = 0; ks < 2; ++ks) {
            bf16x8 a[2], b[8];
            const int kbase = ks * 32 + (lane >> 4) * 8;
#pragma unroll
            for (int i = 0; i < 2; ++i) {
                int r = w * 32 + i * 16 + (lane & 15);
                int kk = kbase ^ ((r & 7) << 3);
                a[i] = *(bf16x8*)&As[r * 64 + kk];
            }
#pragma unroll
            for (int jj = 0; jj < 8; ++jj) {
                int o = jj * 16 + (lane & 15);
                int kk = kbase ^ ((o & 7) << 3);
                b[jj] = *(bf16x8*)&Bs[o * 64 + kk];
            }
#pragma unroll
            for (int i = 0; i < 2; ++i)
#pragma unroll
                for (int jj = 0; jj < 8; ++jj)
                    acc[i][jj] = __builtin_amdgcn_mfma_f32_16x16x32_bf16(a[i], b[jj], acc[i][jj], 0, 0, 0);
        }
    }

#pragma unroll
    for (int i = 0; i < 2; ++i) {
        int mbase = w * 32 + i * 16 + (lane >> 4) * 4;
#pragma unroll
        for (int q = 0; q < 4; ++q) {
            int m = mbase + q;
            int gr = gbase + row0 + m;
            if (row0 + m < rows && gr < N) {
#pragma unroll
                for (int jj = 0; jj < 8; ++jj) {
                    int n = jj * 16 + (lane & 15);
                    out[(size_t)gr * F + n] = fmaxf(acc[i][jj][q], 0.f);
                }
            }
        }
    }
}

extern "C" void kernel_launch(void* const* d_in, const int* in_sizes, int n_in,
                              void* d_out, int out_size, void* d_ws, size_t ws_size,
                              hipStream_t stream) {
    const float* x  = (const float*)d_in[0];
    const float* Wb = (const float*)d_in[1];
    const float* Wc = (const float*)d_in[2];
    const float* ev = (const float*)d_in[3];
    const int*   es = (const int*)d_in[4];
    const int*   ed = (const int*)d_in[5];
    float* out = (float*)d_out;

    const int N = in_sizes[0] / F;
    const int E = in_sizes[3] / NR;

    char* p = (char*)d_ws;
    auto alloc = [&](size_t bytes) -> char* {
        char* q = p;
        p += (bytes + 255) & ~(size_t)255;
        return q;
    };
    unsigned* payload   = (unsigned*)alloc((size_t)NR * E * 4);          // 16 MB
    int* cnt            = (int*)alloc((size_t)NR * N * 4);               // 1.6 MB
    int* offs           = (int*)alloc((size_t)NR * (N + 1) * 4);         // 1.6 MB
    unsigned char* rank = (unsigned char*)alloc((size_t)NR * E);         // 4 MB
    unsigned short* Bt  = (unsigned short*)alloc((size_t)F * NB * F * 2);
    unsigned* xb        = (unsigned*)alloc((size_t)N * F * 2);           // 12.8 MB

    size_t used = (size_t)(p - (char*)d_ws);
    size_t rem = ws_size > used ? ws_size - used : (size_t)(128 * 1024);
    size_t mix_rows = (rem / (512 * 2)) & ~(size_t)127;
    int chunk = (int)(mix_rows < 128 ? 128
                      : (mix_rows > (size_t)N ? (size_t)((N + 127) & ~(size_t)127) : mix_rows));
    unsigned short* mixbuf = (unsigned short*)p;

    hipMemsetAsync(cnt, 0, (size_t)NR * N * 4, stream);
    cvt_x_kernel<<<(N * F / 8 + 255) / 256, 256, 0, stream>>>((const float4*)x, (uint4*)xb, N * F / 8);
    cvt_w_kernel<<<(F * NB * F + 255) / 256, 256, 0, stream>>>(Wb, Bt);

    dim3 eg(((E + 3) / 4 + 255) / 256, NR);
    hist_kernel<<<eg, 256, 0, stream>>>(ed, cnt, rank, E, N);
    scan_kernel<<<NR, 1024, 0, stream>>>(cnt, offs, N);
    fill_kernel<<<eg, 256, 0, stream>>>(es, ev, ed, offs, rank, payload, E, N);

    for (int c0 = 0; c0 < N; c0 += chunk) {
        int crows = min(chunk, N - c0);
        accum_kernel<<<(crows + 3) / 4, 256, 0, stream>>>(xb, payload, offs, Wc,
                                                          (unsigned*)mixbuf, c0, c0 + crows, E, N);
        gemm_mfma<<<(crows + 127) / 128, 256, 0, stream>>>(mixbuf, Bt, out, crows, c0, N);
    }
}

// Round 7
// 478.213 us; speedup vs baseline: 2.3507x; 1.1674x over previous
//
#include <hip/hip_runtime.h>

#define F 128
#define NB 4
#define NR 8

typedef __attribute__((ext_vector_type(8))) short bf16x8;
typedef __attribute__((ext_vector_type(4))) float f32x4;
typedef __attribute__((ext_vector_type(2))) float f32x2;

__device__ __forceinline__ unsigned f2bf(float f) {  // RNE f32->bf16
    unsigned u = __float_as_uint(f);
    return (u + 0x7FFFu + ((u >> 16) & 1u)) >> 16;
}
__device__ __forceinline__ unsigned f2bf2(float lo, float hi) {
    return f2bf(lo) | (f2bf(hi) << 16);
}

// x f32 [N*128] -> bf16, 8 elems/thread
__global__ void cvt_x_kernel(const float4* __restrict__ x4, uint4* __restrict__ xb, int total8) {
    int i = blockIdx.x * blockDim.x + threadIdx.x;
    if (i >= total8) return;
    float4 a = x4[(size_t)i * 2], b = x4[(size_t)i * 2 + 1];
    xb[i] = make_uint4(f2bf2(a.x, a.y), f2bf2(a.z, a.w), f2bf2(b.x, b.y), f2bf2(b.z, b.w));
}

// Bt[o][b*128+k] = bf16(W_basis[b][k][o]) : [128][512]
__global__ void cvt_w_kernel(const float* __restrict__ Wb, unsigned short* __restrict__ Bt) {
    int t = blockIdx.x * blockDim.x + threadIdx.x;
    if (t >= F * NB * F) return;
    int o = t >> 9, bk = t & 511, b = bk >> 7, k = bk & 127;
    Bt[t] = (unsigned short)f2bf(Wb[((size_t)b * F + k) * F + o]);
}

// count per (rel,dst) into cnt[r*N+d]; store per-edge rank (uint8, coalesced).
__global__ void hist_kernel(const int* __restrict__ ed, int* __restrict__ cnt,
                            unsigned char* __restrict__ rank, int E, int N) {
    int e = (blockIdx.x * blockDim.x + threadIdx.x) * 4;
    if (e >= E) return;
    int r = blockIdx.y;
    size_t idx = (size_t)r * E + e;
    int* c = cnt + (size_t)r * N;
    if (e + 3 < E) {
        int4 d4 = *(const int4*)&ed[idx];
        uchar4 rk;
        rk.x = (unsigned char)atomicAdd(&c[d4.x], 1);
        rk.y = (unsigned char)atomicAdd(&c[d4.y], 1);
        rk.z = (unsigned char)atomicAdd(&c[d4.z], 1);
        rk.w = (unsigned char)atomicAdd(&c[d4.w], 1);
        *(uchar4*)&rank[idx] = rk;
    } else {
        for (int k = 0; e + k < E; ++k)
            rank[idx + k] = (unsigned char)atomicAdd(&c[ed[idx + k]], 1);
    }
}

// per-relation exclusive scan: one block per relation over N counts.
__global__ __launch_bounds__(1024) void scan_kernel(const int* __restrict__ cnt,
                                                    int* __restrict__ offs, int N) {
    __shared__ int sums[1024];
    int r = blockIdx.x;
    const int* c = cnt + (size_t)r * N;
    int* o = offs + (size_t)r * (N + 1);
    int t = threadIdx.x;
    int ch = (N + 1023) >> 10;
    int beg = min(t * ch, N), end = min(beg + ch, N);
    int s = 0;
    for (int i = beg; i < end; ++i) s += c[i];
    sums[t] = s;
    __syncthreads();
    for (int dd = 1; dd < 1024; dd <<= 1) {
        int v = (t >= dd) ? sums[t - dd] : 0;
        __syncthreads();
        sums[t] += v;
        __syncthreads();
    }
    int run = (t == 0) ? 0 : sums[t - 1];
    for (int i = beg; i < end; ++i) {
        o[i] = run;
        run += c[i];
    }
    if (t == 1023) o[N] = run;
}

// segdesc[d*8+r] = ((r*E + offs[r][d]) << 8) | min(len,255)  -- one 32B line per dst
__global__ void seg_kernel(const int* __restrict__ cnt, const int* __restrict__ offs,
                           unsigned* __restrict__ segdesc, int N, int E) {
    int d = blockIdx.x * blockDim.x + threadIdx.x;
    if (d >= N) return;
    unsigned out[8];
#pragma unroll
    for (int r = 0; r < NR; ++r) {
        unsigned start = (unsigned)(r * E + offs[(size_t)r * (N + 1) + d]);
        unsigned len = (unsigned)min(cnt[(size_t)r * N + d], 255);
        out[r] = (start << 8) | len;
    }
    *(uint4*)&segdesc[(size_t)d * 8]     = make_uint4(out[0], out[1], out[2], out[3]);
    *(uint4*)&segdesc[(size_t)d * 8 + 4] = make_uint4(out[4], out[5], out[6], out[7]);
}

// place packed (src:16 | val-bf16:16) at r*E + offs[r][d] + rank. No atomics.
__global__ void fill_kernel(const int* __restrict__ es, const float* __restrict__ ev,
                            const int* __restrict__ ed, const int* __restrict__ offs,
                            const unsigned char* __restrict__ rank,
                            unsigned* __restrict__ payload, int E, int N) {
    int e = (blockIdx.x * blockDim.x + threadIdx.x) * 4;
    if (e >= E) return;
    int r = blockIdx.y;
    size_t idx = (size_t)r * E + e;
    const int* o = offs + (size_t)r * (N + 1);
    unsigned* pl = payload + (size_t)r * E;
    if (e + 3 < E) {
        int4 s4 = *(const int4*)&es[idx];
        int4 d4 = *(const int4*)&ed[idx];
        float4 v4 = *(const float4*)&ev[idx];
        uchar4 rk = *(const uchar4*)&rank[idx];
        pl[o[d4.x] + rk.x] = (unsigned)(s4.x & 0xFFFF) | (f2bf(v4.x) << 16);
        pl[o[d4.y] + rk.y] = (unsigned)(s4.y & 0xFFFF) | (f2bf(v4.y) << 16);
        pl[o[d4.z] + rk.z] = (unsigned)(s4.z & 0xFFFF) | (f2bf(v4.z) << 16);
        pl[o[d4.w] + rk.w] = (unsigned)(s4.w & 0xFFFF) | (f2bf(v4.w) << 16);
    } else {
        for (int k = 0; e + k < E; ++k)
            pl[o[ed[idx + k]] + rank[idx + k]] =
                (unsigned)(es[idx + k] & 0xFFFF) | (f2bf(ev[idx + k]) << 16);
    }
}

// one wave per dst. Per relation segment: sr = sum v*x[s] (scalarized payload,
// saddr-form gathers), then a_b += sr*cw_b once per segment.
__global__ __launch_bounds__(256) void accum_kernel(const unsigned* __restrict__ xb,
                                                    const unsigned* __restrict__ payload,
                                                    const unsigned* __restrict__ segdesc,
                                                    const float* __restrict__ comp,
                                                    unsigned* __restrict__ mix,
                                                    int c0, int c1) {
    __shared__ float4 scomp[NR];
    if (threadIdx.x < NR) scomp[threadIdx.x] = ((const float4*)comp)[threadIdx.x];
    __syncthreads();
    int wave = threadIdx.x >> 6, lane = threadIdx.x & 63;
    int d = c0 + blockIdx.x * 4 + wave;
    if (d >= c1) return;
    uint4 sA = *(const uint4*)&segdesc[(size_t)d * 8];
    uint4 sB = *(const uint4*)&segdesc[(size_t)d * 8 + 4];
    unsigned sd[8] = {sA.x, sA.y, sA.z, sA.w, sB.x, sB.y, sB.z, sB.w};

    f32x2 a0 = {0.f, 0.f}, a1 = {0.f, 0.f}, a2 = {0.f, 0.f}, a3 = {0.f, 0.f};
#pragma unroll
    for (int r = 0; r < NR; ++r) {
        unsigned desc = sd[r];
        unsigned j = desc >> 8;
        unsigned je = j + (desc & 255u);
        if (j >= je) continue;
        f32x2 sr = {0.f, 0.f};
        auto edge = [&](unsigned pv) {
            unsigned p = (unsigned)__builtin_amdgcn_readfirstlane((int)pv);
            float v = __uint_as_float(p & 0xFFFF0000u);            // SALU
            unsigned g = xb[(size_t)(p & 0xFFFFu) * 64 + lane];    // saddr + lane*4
            f32x2 xv = {__uint_as_float(g << 16), __uint_as_float(g & 0xFFFF0000u)};
            sr += xv * v;
        };
        if ((j & 1u) && j < je) { edge(payload[j]); ++j; }
        for (; j + 4 <= je; j += 4) {
            uint2 pk0 = *(const uint2*)&payload[j];
            uint2 pk1 = *(const uint2*)&payload[j + 2];
            edge(pk0.x); edge(pk0.y); edge(pk1.x); edge(pk1.y);
        }
        if (j + 2 <= je) {
            uint2 pk = *(const uint2*)&payload[j];
            edge(pk.x); edge(pk.y);
            j += 2;
        }
        if (j < je) edge(payload[j]);
        float4 cw = scomp[r];
        a0 += sr * cw.x;
        a1 += sr * cw.y;
        a2 += sr * cw.z;
        a3 += sr * cw.w;
    }
    unsigned* mrow = mix + (size_t)(d - c0) * 256 + lane;
    mrow[0]   = f2bf2(a0.x, a0.y);
    mrow[64]  = f2bf2(a1.x, a1.y);
    mrow[128] = f2bf2(a2.x, a2.y);
    mrow[192] = f2bf2(a3.x, a3.y);
}

// out[gbase+row][o] = relu( sum_K mix[row][K] * Bt[o][K] ), K=512.
// 4 waves, tile 128x128, BK=64, XOR-swizzled LDS, MFMA 16x16x32 bf16.
__global__ __launch_bounds__(256) void gemm_mfma(const unsigned short* __restrict__ mix,
                                                 const unsigned short* __restrict__ Bt,
                                                 float* __restrict__ out,
                                                 int rows, int gbase, int N) {
    __shared__ unsigned short As[128 * 64];
    __shared__ unsigned short Bs[128 * 64];
    const int t = threadIdx.x;
    const int row0 = blockIdx.x * 128;
    const int w = t >> 6, lane = t & 63;
    f32x4 acc[2][8] = {};

    for (int kt = 0; kt < 8; ++kt) {
        __syncthreads();
        for (int u = t; u < 1024; u += 256) {
            int r = u >> 3, c = u & 7;
            int k8 = c * 8;
            int ks = k8 ^ ((r & 7) << 3);
            uint4 av = make_uint4(0, 0, 0, 0);
            if (row0 + r < rows) av = *(const uint4*)&mix[(size_t)(row0 + r) * 512 + kt * 64 + k8];
            *(uint4*)&As[r * 64 + ks] = av;
            uint4 bv = *(const uint4*)&Bt[(size_t)r * 512 + kt * 64 + k8];
            *(uint4*)&Bs[r * 64 + ks] = bv;
        }
        __syncthreads();
#pragma unroll
        for (int ks = 0; ks < 2; ++ks) {
            bf16x8 a[2], b[8];
            const int kbase = ks * 32 + (lane >> 4) * 8;
#pragma unroll
            for (int i = 0; i < 2; ++i) {
                int r = w * 32 + i * 16 + (lane & 15);
                int kk = kbase ^ ((r & 7) << 3);
                a[i] = *(bf16x8*)&As[r * 64 + kk];
            }
#pragma unroll
            for (int jj = 0; jj < 8; ++jj) {
                int o = jj * 16 + (lane & 15);
                int kk = kbase ^ ((o & 7) << 3);
                b[jj] = *(bf16x8*)&Bs[o * 64 + kk];
            }
#pragma unroll
            for (int i = 0; i < 2; ++i)
#pragma unroll
                for (int jj = 0; jj < 8; ++jj)
                    acc[i][jj] = __builtin_amdgcn_mfma_f32_16x16x32_bf16(a[i], b[jj], acc[i][jj], 0, 0, 0);
        }
    }

#pragma unroll
    for (int i = 0; i < 2; ++i) {
        int mbase = w * 32 + i * 16 + (lane >> 4) * 4;
#pragma unroll
        for (int q = 0; q < 4; ++q) {
            int m = mbase + q;
            int gr = gbase + row0 + m;
            if (row0 + m < rows && gr < N) {
#pragma unroll
                for (int jj = 0; jj < 8; ++jj) {
                    int n = jj * 16 + (lane & 15);
                    out[(size_t)gr * F + n] = fmaxf(acc[i][jj][q], 0.f);
                }
            }
        }
    }
}

extern "C" void kernel_launch(void* const* d_in, const int* in_sizes, int n_in,
                              void* d_out, int out_size, void* d_ws, size_t ws_size,
                              hipStream_t stream) {
    const float* x  = (const float*)d_in[0];
    const float* Wb = (const float*)d_in[1];
    const float* Wc = (const float*)d_in[2];
    const float* ev = (const float*)d_in[3];
    const int*   es = (const int*)d_in[4];
    const int*   ed = (const int*)d_in[5];
    float* out = (float*)d_out;

    const int N = in_sizes[0] / F;
    const int E = in_sizes[3] / NR;

    char* p = (char*)d_ws;
    auto alloc = [&](size_t bytes) -> char* {
        char* q = p;
        p += (bytes + 255) & ~(size_t)255;
        return q;
    };
    unsigned* payload   = (unsigned*)alloc((size_t)NR * E * 4);          // 16 MB
    int* cnt            = (int*)alloc((size_t)NR * N * 4);               // 1.6 MB
    int* offs           = (int*)alloc((size_t)NR * (N + 1) * 4);         // 1.6 MB
    unsigned* segdesc   = (unsigned*)alloc((size_t)N * 8 * 4);           // 1.6 MB
    unsigned char* rank = (unsigned char*)alloc((size_t)NR * E);         // 4 MB
    unsigned short* Bt  = (unsigned short*)alloc((size_t)F * NB * F * 2);
    unsigned* xb        = (unsigned*)alloc((size_t)N * F * 2);           // 12.8 MB

    size_t used = (size_t)(p - (char*)d_ws);
    size_t rem = ws_size > used ? ws_size - used : (size_t)(128 * 1024);
    size_t mix_rows = (rem / (512 * 2)) & ~(size_t)127;
    int chunk = (int)(mix_rows < 128 ? 128
                      : (mix_rows > (size_t)N ? (size_t)((N + 127) & ~(size_t)127) : mix_rows));
    unsigned short* mixbuf = (unsigned short*)p;

    hipMemsetAsync(cnt, 0, (size_t)NR * N * 4, stream);
    cvt_x_kernel<<<(N * F / 8 + 255) / 256, 256, 0, stream>>>((const float4*)x, (uint4*)xb, N * F / 8);
    cvt_w_kernel<<<(F * NB * F + 255) / 256, 256, 0, stream>>>(Wb, Bt);

    dim3 eg(((E + 3) / 4 + 255) / 256, NR);
    hist_kernel<<<eg, 256, 0, stream>>>(ed, cnt, rank, E, N);
    scan_kernel<<<NR, 1024, 0, stream>>>(cnt, offs, N);
    seg_kernel<<<(N + 255) / 256, 256, 0, stream>>>(cnt, offs, segdesc, N, E);
    fill_kernel<<<eg, 256, 0, stream>>>(es, ev, ed, offs, rank, payload, E, N);

    for (int c0 = 0; c0 < N; c0 += chunk) {
        int crows = min(chunk, N - c0);
        accum_kernel<<<(crows + 3) / 4, 256, 0, stream>>>(xb, payload, segdesc, Wc,
                                                          (unsigned*)mixbuf, c0, c0 + crows);
        gemm_mfma<<<(crows + 127) / 128, 256, 0, stream>>>(mixbuf, Bt, out, crows, c0, N);
    }
}